// Round 2
// baseline (1116.010 us; speedup 1.0000x reference)
//
#include <hip/hip_runtime.h>
#include <math.h>

// Problem constants (B=C=1)
#define NPAT 27          // 3^3 patches
#define PATCH 110592     // 48^3 voxels per patch
#define VOL 884736       // 96^3 grid voxels
#define GSBLK 128

#define XT 12            // x tile dim (8 + 2*2 halo)
#define YT 10            // y1 tile dim (8 + 2*1 halo)
#define YW 11            // y1 tile w stride (padded: breaks bank periodicity)

__device__ __forceinline__ float softplusf(float a) {
    // stable softplus = max(a,0) + log1p(exp(-|a|)) — matches jax.nn.softplus
    return fmaxf(a, 0.f) + log1pf(expf(-fabsf(a)));
}

// One full Gauss-Seidel sweep over the 27 patches, fused with extract().
// Each thread owns one patch-voxel p; cur[27] lives in LDS (dynamic i index).
// A reads are the HBM-dominant stream: fully coalesced (p is innermost dim).
__global__ __launch_bounds__(GSBLK) void gs_sweep(
    const float* __restrict__ xf, const float* __restrict__ bg,
    const float* __restrict__ A, float* __restrict__ cur_out)
{
    __shared__ float cur[NPAT * GSBLK];   // 13.8 KB, slot-per-thread, no barriers needed
    const int tid = threadIdx.x;
    const int p = blockIdx.x * GSBLK + tid;      // grid = PATCH/GSBLK exactly
    const int pd = p / 2304;                     // 48*48
    const int r0 = p - pd * 2304;
    const int ph = r0 / 48;
    const int pw = r0 - ph * 48;
    const int gbase = (pd * 96 + ph) * 96 + pw;  // global idx for patch (0,0,0)

    // extract(): init cur[n] = x_field[lin(n,p)]
#pragma unroll
    for (int n = 0; n < NPAT; ++n) {
        const int nd = n / 9, nh = (n / 3) % 3, nw = n % 3;
        const int g = gbase + ((nd * 24) * 96 + nh * 24) * 96 + nw * 24;
        cur[n * GSBLK + tid] = xf[g];
    }

    const float* Ap = A + p;
#pragma unroll 1
    for (int i = 0; i < NPAT; ++i) {
        const float* Ai = Ap + (size_t)i * (NPAT * PATCH);
        float cross = 0.f;
#pragma unroll
        for (int n = 0; n < NPAT; ++n) {           // 27 independent loads -> MLP
            cross += Ai[(size_t)n * PATCH] * cur[n * GSBLK + tid];
        }
        const float aii = Ai[(size_t)i * PATCH];   // L1 hit (just streamed)
        const float xi = cur[i * GSBLK + tid];
        const int id = i / 9, ih = (i / 3) % 3, iw = i % 3;
        const int g = gbase + ((id * 24) * 96 + ih * 24) * 96 + iw * 24;
        const float bi = bg[g];
        const float coupling = cross - aii * xi;
        const float xnew = (bi - coupling) / (softplusf(aii) + 1e-8f);
        cur[i * GSBLK + tid] = xnew;
    }

#pragma unroll
    for (int n = 0; n < NPAT; ++n) {
        cur_out[(size_t)n * PATCH + p] = cur[n * GSBLK + tid];
    }
}

// reconstruct(): gather the <=8 covering patches per voxel, divide by coverage.
__global__ __launch_bounds__(256) void recon(
    const float* __restrict__ cur, float* __restrict__ out)
{
    const int g = blockIdx.x * 256 + threadIdx.x;
    const int gd = g / 9216;                 // 96*96
    const int r = g - gd * 9216;
    const int gh = r / 96;
    const int gw = r - gh * 96;
    const int dlo = max(0, gd / 24 - 1), dhi = min(2, gd / 24);
    const int hlo = max(0, gh / 24 - 1), hhi = min(2, gh / 24);
    const int wlo = max(0, gw / 24 - 1), whi = min(2, gw / 24);
    float sum = 0.f;
    for (int nd = dlo; nd <= dhi; ++nd)
        for (int nh = hlo; nh <= hhi; ++nh)
            for (int nw = wlo; nw <= whi; ++nw) {
                const int n = nd * 9 + nh * 3 + nw;
                const int pp = (gd - 24 * nd) * 2304 + (gh - 24 * nh) * 48 + (gw - 24 * nw);
                sum += cur[(size_t)n * PATCH + pp];
            }
    const int cnt = (dhi - dlo + 1) * (hhi - hlo + 1) * (whi - wlo + 1);
    out[g] = sum / (float)cnt;
}

// Fused conv1+relu+conv2: y1 never touches HBM.
// Tile: 8x8x8 outputs / block (grid 12^3). LDS: xs (halo 2) -> ys (halo 1) -> out.
__global__ __launch_bounds__(256) void fused_conv(
    const float* __restrict__ x,
    const float* __restrict__ w1, const float* __restrict__ b1,
    const float* __restrict__ w2, const float* __restrict__ b2,
    float* __restrict__ out)
{
    __shared__ float xs[XT * XT * XT];          // 6.75 KB
    __shared__ float ys[16 * YT * YT * YW];     // 68.75 KB -> 2 blocks/CU
    const int tid = threadIdx.x;
    const int bw = blockIdx.x % 12;
    const int bh = (blockIdx.x / 12) % 12;
    const int bd = blockIdx.x / 144;
    const int d0 = bd * 8, h0 = bh * 8, w0 = bw * 8;

    // ---- stage 1: x tile + halo 2, zero-padded at volume boundary ----
    for (int l = tid; l < XT * XT * XT; l += 256) {
        const int ld = l / (XT * XT);
        const int r = l - ld * XT * XT;
        const int lh = r / XT, lw = r - lh * XT;
        const int gd = d0 + ld - 2, gh = h0 + lh - 2, gw = w0 + lw - 2;
        float v = 0.f;
        if ((unsigned)gd < 96u && (unsigned)gh < 96u && (unsigned)gw < 96u)
            v = x[(gd * 96 + gh) * 96 + gw];
        xs[l] = v;
    }
    __syncthreads();

    // ---- stage 2: ys = relu(conv1(x)) on 10^3 positions (y1 halo 1) ----
    // Positions whose global coord is outside the volume are ZERO (conv2's
    // zero padding applies to y1, not to a conv of clamped x).
    for (int q = tid; q < YT * YT * YT; q += 256) {
        const int qd = q / (YT * YT);
        const int r = q - qd * YT * YT;
        const int qh = r / YT, qw = r - qh * YT;
        const int gd = d0 + qd - 1, gh = h0 + qh - 1, gw = w0 + qw - 1;
        const bool inb = (unsigned)gd < 96u && (unsigned)gh < 96u && (unsigned)gw < 96u;
        float xv[27];
#pragma unroll
        for (int kd = 0; kd < 3; ++kd)
#pragma unroll
            for (int kh = 0; kh < 3; ++kh)
#pragma unroll
                for (int kw = 0; kw < 3; ++kw)
                    xv[kd * 9 + kh * 3 + kw] =
                        xs[((qd + kd) * XT + (qh + kh)) * XT + (qw + kw)];
#pragma unroll
        for (int c = 0; c < 16; ++c) {
            float acc = b1[c];                   // uniform -> scalar loads
#pragma unroll
            for (int k = 0; k < 27; ++k)
                acc += w1[c * 27 + k] * xv[k];
            ys[((c * YT + qd) * YT + qh) * YW + qw] = inb ? fmaxf(acc, 0.f) : 0.f;
        }
    }
    __syncthreads();

    // ---- stage 3: conv2 from LDS, 2 outputs (w, w+1) per thread ----
    const int ow0 = (tid & 3) * 2;
    const int oh  = (tid >> 2) & 7;
    const int od  = tid >> 5;
    float a0 = b2[0], a1 = a0;
#pragma unroll
    for (int c = 0; c < 16; ++c) {
#pragma unroll
        for (int kd = 0; kd < 3; ++kd)
#pragma unroll
            for (int kh = 0; kh < 3; ++kh) {
                const float* rowp =
                    &ys[((c * YT + od + kd) * YT + (oh + kh)) * YW + ow0];
                const float v0 = rowp[0], v1 = rowp[1], v2 = rowp[2], v3 = rowp[3];
                const float wa = w2[c * 27 + kd * 9 + kh * 3 + 0];
                const float wb = w2[c * 27 + kd * 9 + kh * 3 + 1];
                const float wc = w2[c * 27 + kd * 9 + kh * 3 + 2];
                a0 += wa * v0 + wb * v1 + wc * v2;
                a1 += wa * v1 + wb * v2 + wc * v3;
            }
    }
    const int gd = d0 + od, gh = h0 + oh, gw = w0 + ow0;
    *(float2*)&out[(gd * 96 + gh) * 96 + gw] = make_float2(a0, a1);
}

extern "C" void kernel_launch(void* const* d_in, const int* in_sizes, int n_in,
                              void* d_out, int out_size, void* d_ws, size_t ws_size,
                              hipStream_t stream)
{
    const float* x  = (const float*)d_in[0];
    const float* b  = (const float*)d_in[1];
    const float* A  = (const float*)d_in[2];
    const float* W1 = (const float*)d_in[3];
    const float* b1 = (const float*)d_in[4];
    const float* W2 = (const float*)d_in[5];
    const float* b2 = (const float*)d_in[6];
    float* out = (float*)d_out;

    // workspace partition
    float* cur  = (float*)d_ws;                        // 27*PATCH
    float* xr   = cur + (size_t)NPAT * PATCH;          // VOL
    float* xnxt = xr + VOL;                            // VOL

    const int gsGrid = PATCH / GSBLK;   // 864
    const int rGrid  = VOL / 256;       // 3456
    const int fGrid  = 12 * 12 * 12;    // 1728

    // iteration 1
    gs_sweep<<<gsGrid, GSBLK, 0, stream>>>(x, b, A, cur);
    recon<<<rGrid, 256, 0, stream>>>(cur, xr);
    fused_conv<<<fGrid, 256, 0, stream>>>(xr, W1, b1, W2, b2, xnxt);
    // iteration 2
    gs_sweep<<<gsGrid, GSBLK, 0, stream>>>(xnxt, b, A, cur);
    recon<<<rGrid, 256, 0, stream>>>(cur, xr);
    fused_conv<<<fGrid, 256, 0, stream>>>(xr, W1, b1, W2, b2, out);
}

// Round 3
// 676.456 us; speedup vs baseline: 1.6498x; 1.6498x over previous
//
#include <hip/hip_runtime.h>
#include <math.h>

// Problem constants (B=C=1)
#define NPAT 27          // 3^3 patches
#define PATCH 110592     // 48^3 voxels per patch
#define VOL 884736       // 96^3 grid voxels
#define GSBLK 128

#define XT 12            // x tile dim (8 + 2*2 halo)
#define YT 10            // y1 tile dim (8 + 2*1 halo)
#define YW 11            // y1 tile w stride (odd: bank-conflict-free)

__device__ __forceinline__ float softplusf(float a) {
    // stable softplus = max(a,0) + log1p(exp(-|a|)) — matches jax.nn.softplus
    return fmaxf(a, 0.f) + log1pf(expf(-fabsf(a)));
}

// One full Gauss-Seidel sweep over the 27 patches, fused with extract().
// Each thread owns one patch-voxel p; cur[27] lives in LDS (dynamic i index).
// A reads are the HBM-dominant stream: fully coalesced, nontemporal (322 MB
// streamed once per sweep — keep L2 for cur/b/x).
__global__ __launch_bounds__(GSBLK) void gs_sweep(
    const float* __restrict__ xf, const float* __restrict__ bg,
    const float* __restrict__ A, float* __restrict__ cur_out)
{
    __shared__ float cur[NPAT * GSBLK];   // 13.8 KB, slot-per-thread, no barriers needed
    const int tid = threadIdx.x;
    const int p = blockIdx.x * GSBLK + tid;      // grid = PATCH/GSBLK exactly
    const int pd = p / 2304;                     // 48*48
    const int r0 = p - pd * 2304;
    const int ph = r0 / 48;
    const int pw = r0 - ph * 48;
    const int gbase = (pd * 96 + ph) * 96 + pw;  // global idx for patch (0,0,0)

    // extract(): init cur[n] = x_field[lin(n,p)]
#pragma unroll
    for (int n = 0; n < NPAT; ++n) {
        const int nd = n / 9, nh = (n / 3) % 3, nw = n % 3;
        const int g = gbase + ((nd * 24) * 96 + nh * 24) * 96 + nw * 24;
        cur[n * GSBLK + tid] = xf[g];
    }

    const float* Ap = A + p;
#pragma unroll 1
    for (int i = 0; i < NPAT; ++i) {
        const float* Ai = Ap + (size_t)i * (NPAT * PATCH);
        float cross = 0.f;
#pragma unroll
        for (int n = 0; n < NPAT; ++n) {           // 27 independent loads -> MLP
            cross += __builtin_nontemporal_load(&Ai[(size_t)n * PATCH]) *
                     cur[n * GSBLK + tid];
        }
        const float aii = Ai[(size_t)i * PATCH];   // L2 hit (just streamed)
        const float xi = cur[i * GSBLK + tid];
        const int id = i / 9, ih = (i / 3) % 3, iw = i % 3;
        const int g = gbase + ((id * 24) * 96 + ih * 24) * 96 + iw * 24;
        const float bi = bg[g];
        const float coupling = cross - aii * xi;
        const float xnew = (bi - coupling) / (softplusf(aii) + 1e-8f);
        cur[i * GSBLK + tid] = xnew;
    }

#pragma unroll
    for (int n = 0; n < NPAT; ++n) {
        cur_out[(size_t)n * PATCH + p] = cur[n * GSBLK + tid];
    }
}

// Fused reconstruct + conv1 + relu + conv2. recon is folded into the stage-1
// LDS load (gather <=8 covering patches / analytic CNT); y1 lives only in LDS.
// Tile: 8x8x8 outputs / block (grid 12^3).
// Stage 2: 200 strips of 5-wide — x window (63 regs) loaded once per strip,
// weights fetched once per channel (batched s_load) -> 5 FMA per weight load.
// Stage 3: 128 strips of 4-wide -> 4 FMA per weight load.
__global__ __launch_bounds__(256) void fused_conv(
    const float* __restrict__ curp,
    const float* __restrict__ w1, const float* __restrict__ b1,
    const float* __restrict__ w2, const float* __restrict__ b2,
    float* __restrict__ out)
{
    __shared__ float xs[XT * XT * XT];          // 6.75 KB
    __shared__ float ys[16 * YT * YT * YW];     // 68.75 KB -> 2 blocks/CU
    const int tid = threadIdx.x;
    const int bw = blockIdx.x % 12;
    const int bh = (blockIdx.x / 12) % 12;
    const int bd = blockIdx.x / 144;
    const int d0 = bd * 8, h0 = bh * 8, w0 = bw * 8;

    // ---- stage 1: reconstruct() into x tile (+halo 2), zero outside volume ----
    for (int l = tid; l < XT * XT * XT; l += 256) {
        const int ld = l / (XT * XT);
        const int r = l - ld * XT * XT;
        const int lh = r / XT, lw = r - lh * XT;
        const int gd = d0 + ld - 2, gh = h0 + lh - 2, gw = w0 + lw - 2;
        float v = 0.f;
        if ((unsigned)gd < 96u && (unsigned)gh < 96u && (unsigned)gw < 96u) {
            const int dlo = max(0, gd / 24 - 1), dhi = min(2, gd / 24);
            const int hlo = max(0, gh / 24 - 1), hhi = min(2, gh / 24);
            const int wlo = max(0, gw / 24 - 1), whi = min(2, gw / 24);
            float sum = 0.f;
            for (int nd = dlo; nd <= dhi; ++nd)
                for (int nh = hlo; nh <= hhi; ++nh)
                    for (int nw = wlo; nw <= whi; ++nw) {
                        const int n = nd * 9 + nh * 3 + nw;
                        const int pp = (gd - 24 * nd) * 2304 +
                                       (gh - 24 * nh) * 48 + (gw - 24 * nw);
                        sum += curp[(size_t)n * PATCH + pp];
                    }
            const int cnt = (dhi - dlo + 1) * (hhi - hlo + 1) * (whi - wlo + 1);
            v = sum / (float)cnt;
        }
        xs[l] = v;
    }
    __syncthreads();

    // ---- stage 2: ys = relu(conv1(x)) on 10^3 positions, 5-wide strips ----
    if (tid < 200) {
        const int sd = tid / 20;             // 0..9
        const int rr = tid - sd * 20;
        const int sh = rr >> 1;              // 0..9
        const int sw0 = (rr & 1) * 5;        // 0 or 5
        // x window 3x3x7 -> registers, loaded ONCE for all 16 channels
        float xv[63];
#pragma unroll
        for (int kd = 0; kd < 3; ++kd)
#pragma unroll
            for (int kh = 0; kh < 3; ++kh)
#pragma unroll
                for (int j = 0; j < 7; ++j)
                    xv[(kd * 3 + kh) * 7 + j] =
                        xs[((sd + kd) * XT + (sh + kh)) * XT + sw0 + j];
        // out-of-volume y1 positions must be ZERO (conv2's zero padding)
        const int gdq = d0 + sd - 1, ghq = h0 + sh - 1;
        const bool okdh = ((unsigned)gdq < 96u) && ((unsigned)ghq < 96u);
        float msk[5];
#pragma unroll
        for (int j = 0; j < 5; ++j)
            msk[j] = (okdh && (unsigned)(w0 + sw0 + j - 1) < 96u) ? 1.f : 0.f;

#pragma unroll 1
        for (int c = 0; c < 16; ++c) {
            float wr[27];
#pragma unroll
            for (int k = 0; k < 27; ++k) wr[k] = w1[c * 27 + k]; // batched s_load
            const float bb = b1[c];
            float acc[5] = {bb, bb, bb, bb, bb};
#pragma unroll
            for (int kd = 0; kd < 3; ++kd)
#pragma unroll
                for (int kh = 0; kh < 3; ++kh)
#pragma unroll
                    for (int kw = 0; kw < 3; ++kw) {
                        const float wgt = wr[kd * 9 + kh * 3 + kw];
                        const float* xvr = &xv[(kd * 3 + kh) * 7 + kw];
#pragma unroll
                        for (int j = 0; j < 5; ++j)
                            acc[j] += wgt * xvr[j];
                    }
            float* yrow = &ys[((c * YT + sd) * YT + sh) * YW + sw0];
#pragma unroll
            for (int j = 0; j < 5; ++j)
                yrow[j] = fmaxf(acc[j], 0.f) * msk[j];
        }
    }
    __syncthreads();

    // ---- stage 3: conv2 from LDS, 128 strips of 4-wide ----
    if (tid < 128) {
        const int ow0 = (tid & 1) * 4;
        const int oh = (tid >> 1) & 7;
        const int od = tid >> 4;
        const float bb = b2[0];
        float a0 = bb, a1 = bb, a2 = bb, a3 = bb;
#pragma unroll 1
        for (int c = 0; c < 16; ++c) {
            float wr[27];
#pragma unroll
            for (int k = 0; k < 27; ++k) wr[k] = w2[c * 27 + k];
#pragma unroll
            for (int kd = 0; kd < 3; ++kd)
#pragma unroll
                for (int kh = 0; kh < 3; ++kh) {
                    const float* rowp =
                        &ys[((c * YT + od + kd) * YT + (oh + kh)) * YW + ow0];
                    const float v0 = rowp[0], v1 = rowp[1], v2 = rowp[2];
                    const float v3 = rowp[3], v4 = rowp[4], v5 = rowp[5];
                    const float wa = wr[kd * 9 + kh * 3 + 0];
                    const float wb = wr[kd * 9 + kh * 3 + 1];
                    const float wc = wr[kd * 9 + kh * 3 + 2];
                    a0 += wa * v0 + wb * v1 + wc * v2;
                    a1 += wa * v1 + wb * v2 + wc * v3;
                    a2 += wa * v2 + wb * v3 + wc * v4;
                    a3 += wa * v3 + wb * v4 + wc * v5;
                }
        }
        const int gd = d0 + od, gh = h0 + oh, gw = w0 + ow0;
        *(float4*)&out[(gd * 96 + gh) * 96 + gw] = make_float4(a0, a1, a2, a3);
    }
}

extern "C" void kernel_launch(void* const* d_in, const int* in_sizes, int n_in,
                              void* d_out, int out_size, void* d_ws, size_t ws_size,
                              hipStream_t stream)
{
    const float* x  = (const float*)d_in[0];
    const float* b  = (const float*)d_in[1];
    const float* A  = (const float*)d_in[2];
    const float* W1 = (const float*)d_in[3];
    const float* b1 = (const float*)d_in[4];
    const float* W2 = (const float*)d_in[5];
    const float* b2 = (const float*)d_in[6];
    float* out = (float*)d_out;

    // workspace partition
    float* cur  = (float*)d_ws;                        // 27*PATCH
    float* xnxt = cur + (size_t)NPAT * PATCH;          // VOL

    const int gsGrid = PATCH / GSBLK;   // 864
    const int fGrid  = 12 * 12 * 12;    // 1728

    // iteration 1
    gs_sweep<<<gsGrid, GSBLK, 0, stream>>>(x, b, A, cur);
    fused_conv<<<fGrid, 256, 0, stream>>>(cur, W1, b1, W2, b2, xnxt);
    // iteration 2
    gs_sweep<<<gsGrid, GSBLK, 0, stream>>>(xnxt, b, A, cur);
    fused_conv<<<fGrid, 256, 0, stream>>>(cur, W1, b1, W2, b2, out);
}